// Round 3
// baseline (168.235 us; speedup 1.0000x reference)
//
#include <hip/hip_runtime.h>
#include <hip/hip_fp16.h>
#include <math.h>

#define D_FEAT 100
#define ROW_STRIDE 300     // 3 * D_FEAT concatenated output blocks
#define ROWB 208u          // f16 table row: 13 x 16B blocks; block k = feats
                           // 8k..8k+7 as f16 (block 12: feats 96..99 + 4 zero)

// ---------------------------------------------------------------------------
// fast tanh via hardware exp (inputs bounded, |2x| <= ~12)
// ---------------------------------------------------------------------------
__device__ __forceinline__ float fast_tanh(float x) {
    float ax = fabsf(x);
    float e  = __expf(2.f * ax);
    float t  = 1.f - 2.f / (e + 1.f);
    return copysignf(t, x);
}

// f16 packing (RNE)
__device__ __forceinline__ unsigned pack_f16x2(float a, float b) {
    __half2 h = __floats2half2_rn(a, b);
    union { __half2 h; unsigned u; } cvt; cvt.h = h;
    return cvt.u;
}

// butterfly sum within each 32-lane half
__device__ __forceinline__ float half_reduce(float v) {
    #pragma unroll
    for (int off = 16; off; off >>= 1) v += __shfl_xor(v, off, 64);
    return v;
}
// butterfly sum across all 64 lanes
__device__ __forceinline__ float full_reduce(float v) {
    #pragma unroll
    for (int off = 32; off; off >>= 1) v += __shfl_xor(v, off, 64);
    return v;
}

// ---------------------------------------------------------------------------
// Kernel 1: 2 nodes per wave + fused CSR binary search. (unchanged layout)
// ---------------------------------------------------------------------------
__global__ __launch_bounds__(256) void tanh_score_kernel(
    const float* __restrict__ features,
    float* __restrict__ out,
    unsigned long long* __restrict__ tab0,   // 208-B f16 row table or null
    float* __restrict__ escore0,             // per-node exp-score (always)
    const float* __restrict__ none_rel,
    const int* __restrict__ adj,
    int* __restrict__ startArr,
    int E, int N)
{
    int gtid = blockIdx.x * blockDim.x + threadIdx.x;
    if (gtid <= N) {                          // fused CSR
        if (gtid == N) startArr[N] = E;
        else {
            int lo = 0, hi = E;
            while (lo < hi) {
                int mid = (lo + hi) >> 1;
                if (adj[2 * mid] < gtid) lo = mid + 1; else hi = mid;
            }
            startArr[gtid] = lo;
        }
    }

    int waveId = gtid >> 6;
    int lane = threadIdx.x & 63;
    int h32  = lane >> 5;
    int l    = lane & 31;
    int n    = waveId * 2 + h32;
    const bool valid_n = (n < N);
    const bool fact = valid_n && (l >= 1) && (l <= 25);

    float x0 = 0.f, x1 = 0.f, x2 = 0.f, x3 = 0.f;
    if (fact) {
        float4 f = ((const float4*)(features + (size_t)n * D_FEAT))[l - 1];
        x0 = fast_tanh(f.x); x1 = fast_tanh(f.y);
        x2 = fast_tanh(f.z); x3 = fast_tanh(f.w);
        ((float4*)(out + (size_t)n * ROW_STRIDE))[l - 1] = make_float4(x0, x1, x2, x3);
    }
    if (tab0 && valid_n) {
        char* row = (char*)tab0 + (size_t)n * ROWB;
        if (l >= 1 && l <= 25) {
            unsigned long long q = (unsigned long long)pack_f16x2(x0, x1) |
                                   ((unsigned long long)pack_f16x2(x2, x3) << 32);
            *(unsigned long long*)(row + 8 * (l - 1)) = q;   // feats 4(l-1)..
        } else if (l == 26) {
            *(unsigned long long*)(row + 200) = 0ULL;        // zero pads 100..103
        }
    }

    float nx = 0.f, ny = 0.f, nz = 0.f, nw = 0.f;
    if (l >= 1 && l <= 25) {
        float4 v = ((const float4*)none_rel)[l - 1];
        nx = v.x; ny = v.y; nz = v.z; nw = v.w;
    }
    float ss = half_reduce(nx * nx + ny * ny + nz * nz + nw * nw);
    float inv_nr = 1.f / fmaxf(sqrtf(ss), 1e-12f);

    float dot = half_reduce(x0 * nx + x1 * ny + x2 * nz + x3 * nw) * inv_nr;
    float sq  = half_reduce(x0 * x0 + x1 * x1 + x2 * x2 + x3 * x3);
    if (l == 0 && valid_n) {
        float es = __expf(-dot / fmaxf(sqrtf(sq), 1e-12f));
        escore0[n] = es;
    }
}

// ---------------------------------------------------------------------------
// Kernel 2: fused attention layer, ONE node per wave, FOUR edges per pass.
//  Lanes 0..51 = 4 groups of 13; group g, sub-lane li handles 16-B block li
//  of edge 4p+g on pass p. Batches of 4 passes: 8 register shfls, then 4
//  independent uint4 gathers issued back-to-back (4 gathers in flight),
//  then 32 v_fma_mix. Mean degree 16 => whole node is ONE batch, one
//  vmcnt wait instead of ~8 serial gather latencies.
//  Weights staged per-edge (w=0 beyond deg) => no masking in hot loop.
// ---------------------------------------------------------------------------
template <bool WRITE_TAB>
__global__ __launch_bounds__(256) void attn4_kernel(
    const unsigned long long* __restrict__ tab,   // prev 208-B f16 table
    float* __restrict__ outp,
    unsigned long long* __restrict__ tab_out,     // next table (WRITE_TAB)
    const int2* __restrict__ adj2,
    const int* __restrict__ start,
    const float* __restrict__ esc_in,             // per-node weights (f32)
    float* __restrict__ esc_out,                  // next weights (WRITE_TAB)
    const float* __restrict__ none_rel,
    int N)
{
    const int n    = (int)((blockIdx.x * blockDim.x + threadIdx.x) >> 6);
    const int lane = threadIdx.x & 63;
    const int g    = lane / 13;            // group 0..3 (lanes 52..63: g=4, idle)
    const int li   = lane - 13 * g;        // 0..12 within group
    const bool actA = (lane < 13);
    const bool valid_n = (n < N);

    int e0 = 0, e1 = 0;
    if (valid_n) { e0 = start[n]; e1 = start[n + 1]; }
    const int deg = e1 - e0;

    // stage cols + weights for up to 64 edges (lane l holds edge l)
    int cst = 0; float wst = 0.f;
    if (lane < deg) { cst = adj2[e0 + lane].y; wst = esc_in[cst]; }

    // denominator: sum of staged weights (zeros beyond deg; tail added later)
    float dsum = full_reduce(wst);

    const char* tb = (const char*)tab;
    const unsigned suboff = (unsigned)(li * 16);   // g==4: li<=11, still valid

    float a0=0.f,a1=0.f,a2=0.f,a3=0.f,a4=0.f,a5=0.f,a6=0.f,a7=0.f;

    const int cap = deg < 64 ? deg : 64;
    const int npass = (cap + 3) >> 2;              // 4 edges per pass

    for (int p0 = 0; p0 < npass; p0 += 4) {
        // ---- 8 register shfls (edge col + weight for 16 edge-slots) ----
        const int i0 = (4 * (p0 + 0) + g) & 63;
        const int i1 = (4 * (p0 + 1) + g) & 63;
        const int i2 = (4 * (p0 + 2) + g) & 63;
        const int i3 = (4 * (p0 + 3) + g) & 63;
        int   cc0 = __shfl(cst, i0, 64), cc1 = __shfl(cst, i1, 64);
        int   cc2 = __shfl(cst, i2, 64), cc3 = __shfl(cst, i3, 64);
        float ww0 = __shfl(wst, i0, 64), ww1 = __shfl(wst, i1, 64);
        float ww2 = __shfl(wst, i2, 64), ww3 = __shfl(wst, i3, 64);
        // edge-slots beyond deg: staged w = 0, col = 0 (harmless row-0 load)

        // ---- 4 independent gathers, all in flight ----
        const uint4 v0 = *(const uint4*)(tb + (size_t)((unsigned)cc0 * ROWB + suboff));
        const uint4 v1 = *(const uint4*)(tb + (size_t)((unsigned)cc1 * ROWB + suboff));
        const uint4 v2 = *(const uint4*)(tb + (size_t)((unsigned)cc2 * ROWB + suboff));
        const uint4 v3 = *(const uint4*)(tb + (size_t)((unsigned)cc3 * ROWB + suboff));

        // ---- 32 fused mixed-precision FMAs ----
        const __half2* h0 = (const __half2*)&v0;
        const __half2* h1 = (const __half2*)&v1;
        const __half2* h2 = (const __half2*)&v2;
        const __half2* h3 = (const __half2*)&v3;
        a0 = fmaf(__low2float(h0[0]),  ww0, a0);
        a1 = fmaf(__high2float(h0[0]), ww0, a1);
        a2 = fmaf(__low2float(h0[1]),  ww0, a2);
        a3 = fmaf(__high2float(h0[1]), ww0, a3);
        a4 = fmaf(__low2float(h0[2]),  ww0, a4);
        a5 = fmaf(__high2float(h0[2]), ww0, a5);
        a6 = fmaf(__low2float(h0[3]),  ww0, a6);
        a7 = fmaf(__high2float(h0[3]), ww0, a7);
        a0 = fmaf(__low2float(h1[0]),  ww1, a0);
        a1 = fmaf(__high2float(h1[0]), ww1, a1);
        a2 = fmaf(__low2float(h1[1]),  ww1, a2);
        a3 = fmaf(__high2float(h1[1]), ww1, a3);
        a4 = fmaf(__low2float(h1[2]),  ww1, a4);
        a5 = fmaf(__high2float(h1[2]), ww1, a5);
        a6 = fmaf(__low2float(h1[3]),  ww1, a6);
        a7 = fmaf(__high2float(h1[3]), ww1, a7);
        a0 = fmaf(__low2float(h2[0]),  ww2, a0);
        a1 = fmaf(__high2float(h2[0]), ww2, a1);
        a2 = fmaf(__low2float(h2[1]),  ww2, a2);
        a3 = fmaf(__high2float(h2[1]), ww2, a3);
        a4 = fmaf(__low2float(h2[2]),  ww2, a4);
        a5 = fmaf(__high2float(h2[2]), ww2, a5);
        a6 = fmaf(__low2float(h2[3]),  ww2, a6);
        a7 = fmaf(__high2float(h2[3]), ww2, a7);
        a0 = fmaf(__low2float(h3[0]),  ww3, a0);
        a1 = fmaf(__high2float(h3[0]), ww3, a1);
        a2 = fmaf(__low2float(h3[1]),  ww3, a2);
        a3 = fmaf(__high2float(h3[1]), ww3, a3);
        a4 = fmaf(__low2float(h3[2]),  ww3, a4);
        a5 = fmaf(__high2float(h3[2]), ww3, a5);
        a6 = fmaf(__low2float(h3[3]),  ww3, a6);
        a7 = fmaf(__high2float(h3[3]), ww3, a7);
    }

    // deg > 64 tail (~never): one edge per pass, group 0 accumulates
    for (int e = e0 + 64; e < e1; ++e) {
        int   c = adj2[e].y;
        float w = esc_in[c];
        const uint4 v = *(const uint4*)(tb + (size_t)((unsigned)c * ROWB + suboff));
        const __half2* hv = (const __half2*)&v;
        if (g == 0) {
            a0 = fmaf(__low2float(hv[0]),  w, a0);
            a1 = fmaf(__high2float(hv[0]), w, a1);
            a2 = fmaf(__low2float(hv[1]),  w, a2);
            a3 = fmaf(__high2float(hv[1]), w, a3);
            a4 = fmaf(__low2float(hv[2]),  w, a4);
            a5 = fmaf(__high2float(hv[2]), w, a5);
            a6 = fmaf(__low2float(hv[3]),  w, a6);
            a7 = fmaf(__high2float(hv[3]), w, a7);
        }
        dsum += w;     // uniform across lanes
    }

    // ---- combine groups: {0,1} += {2,3}, then {0} += {1} ----
    const int pr1 = (lane + 26) & 63;
    a0 += __shfl(a0, pr1, 64); a1 += __shfl(a1, pr1, 64);
    a2 += __shfl(a2, pr1, 64); a3 += __shfl(a3, pr1, 64);
    a4 += __shfl(a4, pr1, 64); a5 += __shfl(a5, pr1, 64);
    a6 += __shfl(a6, pr1, 64); a7 += __shfl(a7, pr1, 64);
    const int pr2 = (lane + 13) & 63;
    a0 += __shfl(a0, pr2, 64); a1 += __shfl(a1, pr2, 64);
    a2 += __shfl(a2, pr2, 64); a3 += __shfl(a3, pr2, 64);
    a4 += __shfl(a4, pr2, 64); a5 += __shfl(a5, pr2, 64);
    a6 += __shfl(a6, pr2, 64); a7 += __shfl(a7, pr2, 64);

    const float inv_d = (deg > 0) ? 1.f / dsum : 0.f;
    float r0 = fast_tanh(a0 * inv_d);
    float r1 = fast_tanh(a1 * inv_d);
    float r2 = fast_tanh(a2 * inv_d);
    float r3 = fast_tanh(a3 * inv_d);
    float r4 = fast_tanh(a4 * inv_d);
    float r5 = fast_tanh(a5 * inv_d);
    float r6 = fast_tanh(a6 * inv_d);
    float r7 = fast_tanh(a7 * inv_d);
    if (!actA) { r0=r1=r2=r3=r4=r5=r6=r7=0.f; }   // epilogue reduce correctness

    // ---- writes: f32 out (+ f16 table) ----
    if (valid_n && actA) {
        const int l = lane;                       // 0..12
        float4* orow = (float4*)(outp + (size_t)n * ROW_STRIDE);
        orow[2*l] = make_float4(r0, r1, r2, r3);          // feats 8l..8l+3
        if (l < 12)
            orow[2*l + 1] = make_float4(r4, r5, r6, r7);  // feats 8l+4..8l+7
        if constexpr (WRITE_TAB) {
            uint4* trow = (uint4*)((char*)tab_out + (size_t)n * ROWB);
            trow[l] = make_uint4(pack_f16x2(r0, r1), pack_f16x2(r2, r3),
                                 pack_f16x2(r4, r5), pack_f16x2(r6, r7));
            // lane 12: r4..r7 == 0 -> pads stay zero
        }
    }

    // ---- epilogue: next layer's exp-score ----
    if constexpr (WRITE_TAB) {
        const int l = lane;
        float n0=0.f,n1=0.f,n2=0.f,n3=0.f,n4=0.f,n5=0.f,n6=0.f,n7=0.f;
        if (actA) {
            float4 u = *(const float4*)(none_rel + 8 * l);
            n0=u.x; n1=u.y; n2=u.z; n3=u.w;
            if (l < 12) {
                float4 v2 = *(const float4*)(none_rel + 8 * l + 4);
                n4=v2.x; n5=v2.y; n6=v2.z; n7=v2.w;
            }
        }
        float ss = half_reduce(n0*n0+n1*n1+n2*n2+n3*n3+n4*n4+n5*n5+n6*n6+n7*n7);
        float inv_nr = 1.f / fmaxf(sqrtf(ss), 1e-12f);
        float dot = half_reduce(r0*n0+r1*n1+r2*n2+r3*n3+r4*n4+r5*n5+r6*n6+r7*n7) * inv_nr;
        float sq  = half_reduce(r0*r0+r1*r1+r2*r2+r3*r3+r4*r4+r5*r5+r6*r6+r7*r7);
        if (lane == 0 && valid_n) {
            float es = __expf(-dot / fmaxf(sqrtf(sq), 1e-12f));
            esc_out[n] = es;
        }
    }
}

// ---------------------------------------------------------------------------
// Fallback attention kernel (f32 path, only used when workspace is too small
// for the f16 tables).
// ---------------------------------------------------------------------------
__global__ __launch_bounds__(256) void attn_f32_kernel(
    const float* __restrict__ prev,          // f32 stride-300
    float* __restrict__ outp,
    const int2* __restrict__ adj2,
    const int* __restrict__ start,
    const float* __restrict__ escore_in,
    float* __restrict__ escore_out,
    const float* __restrict__ none_rel,
    int N)
{
    int waveId = (int)((blockIdx.x * blockDim.x + threadIdx.x) >> 6);
    int lane = threadIdx.x & 63;
    int h32  = lane >> 5;
    int l    = lane & 31;
    int n    = waveId * 2 + h32;
    const bool valid_n = (n < N);
    const bool fact = valid_n && (l >= 1) && (l <= 25);
    const int base = h32 << 5;

    int e0 = 0, e1 = 0;
    if (valid_n) { e0 = start[n]; e1 = start[n + 1]; }
    const int deg = e1 - e0;

    int   c0 = 0, c1 = 0;
    float w0 = 0.f, w1 = 0.f;
    if (l < deg)      { c0 = adj2[e0 + l].y;      w0 = escore_in[c0]; }
    if (l + 32 < deg) { c1 = adj2[e0 + l + 32].y; w1 = escore_in[c1]; }

    int maxdeg = deg;
    { int o = __shfl_xor(maxdeg, 32, 64); maxdeg = maxdeg > o ? maxdeg : o; }

    float d_acc = 0.f, a0 = 0.f, a1 = 0.f, a2 = 0.f, a3 = 0.f;
    const int cap1 = maxdeg < 32 ? maxdeg : 32;
    for (int r = 0; r < cap1; r += 8) {
        #pragma unroll
        for (int j = 0; j < 8; ++j) {
            int   i = r + j;
            int   c = __shfl(c0, base + i, 64);
            float w = __shfl(w0, base + i, 64);
            float p0 = 0.f, p1 = 0.f, p2 = 0.f, p3 = 0.f;
            if (fact && (i < deg)) {
                float4 v = ((const float4*)(prev + (size_t)c * ROW_STRIDE))[l - 1];
                p0 = v.x; p1 = v.y; p2 = v.z; p3 = v.w;
            }
            if (i >= deg) w = 0.f;
            d_acc += w;
            a0 += w * p0; a1 += w * p1; a2 += w * p2; a3 += w * p3;
        }
    }
    const int cap2 = maxdeg < 64 ? maxdeg : 64;
    for (int r = 32; r < cap2; r += 8) {
        #pragma unroll
        for (int j = 0; j < 8; ++j) {
            int   i = r + j;
            int   c = __shfl(c1, base + i - 32, 64);
            float w = __shfl(w1, base + i - 32, 64);
            float p0 = 0.f, p1 = 0.f, p2 = 0.f, p3 = 0.f;
            if (fact && (i < deg)) {
                float4 v = ((const float4*)(prev + (size_t)c * ROW_STRIDE))[l - 1];
                p0 = v.x; p1 = v.y; p2 = v.z; p3 = v.w;
            }
            if (i >= deg) w = 0.f;
            d_acc += w;
            a0 += w * p0; a1 += w * p1; a2 += w * p2; a3 += w * p3;
        }
    }
    for (int e = e0 + 64; e < e1; ++e) {
        int c = adj2[e].y;
        float w = escore_in[c];
        float p0 = 0.f, p1 = 0.f, p2 = 0.f, p3 = 0.f;
        if (fact) {
            float4 v = ((const float4*)(prev + (size_t)c * ROW_STRIDE))[l - 1];
            p0 = v.x; p1 = v.y; p2 = v.z; p3 = v.w;
        }
        d_acc += w;
        a0 += w * p0; a1 += w * p1; a2 += w * p2; a3 += w * p3;
    }

    const float inv_d = (deg > 0) ? 1.f / d_acc : 0.f;
    float r0 = fast_tanh(a0 * inv_d);
    float r1 = fast_tanh(a1 * inv_d);
    float r2 = fast_tanh(a2 * inv_d);
    float r3 = fast_tanh(a3 * inv_d);
    if (fact) {
        ((float4*)(outp + (size_t)n * ROW_STRIDE))[l - 1] = make_float4(r0, r1, r2, r3);
    } else {
        r0 = r1 = r2 = r3 = 0.f;
    }

    if (escore_out) {
        float nx = 0.f, ny = 0.f, nz = 0.f, nw = 0.f;
        if (l >= 1 && l <= 25) {
            float4 v = ((const float4*)none_rel)[l - 1];
            nx = v.x; ny = v.y; nz = v.z; nw = v.w;
        }
        float ss = half_reduce(nx * nx + ny * ny + nz * nz + nw * nw);
        float inv_nr = 1.f / fmaxf(sqrtf(ss), 1e-12f);
        float dot = half_reduce(r0 * nx + r1 * ny + r2 * nz + r3 * nw) * inv_nr;
        float sq  = half_reduce(r0 * r0 + r1 * r1 + r2 * r2 + r3 * r3);
        if (l == 0 && valid_n) {
            float es = __expf(-dot / fmaxf(sqrtf(sq), 1e-12f));
            escore_out[n] = es;
        }
    }
}

// ---------------------------------------------------------------------------
extern "C" void kernel_launch(void* const* d_in, const int* in_sizes, int n_in,
                              void* d_out, int out_size, void* d_ws, size_t ws_size,
                              hipStream_t stream) {
    const float* features = (const float*)d_in[0];
    // d_in[1] = rel_emb: unused by the reference
    const int*   adj      = (const int*)d_in[2];
    const float* none_rel = (const float*)d_in[3];
    float* out = (float*)d_out;

    const int N = in_sizes[0] / D_FEAT;   // 50000
    const int E = in_sizes[2] / 2;        // 800000

    // ws: start[N+1] | escore0[N] | escore1[N] | tab0[N*208B] | tab1[N*208B]
    size_t off = 0;
    auto take = [&](size_t bytes) { size_t o = off; off = (off + bytes + 15) & ~(size_t)15; return o; };
    char* w = (char*)d_ws;
    int*   start   = (int*)  (w + take(sizeof(int)   * (size_t)(N + 1)));
    float* escore0 = (float*)(w + take(sizeof(float) * (size_t)N));
    float* escore1 = (float*)(w + take(sizeof(float) * (size_t)N));
    size_t tab_off0 = take((size_t)N * ROWB);
    size_t tab_off1 = take((size_t)N * ROWB);
    const bool use_tab = (ws_size >= off);
    unsigned long long* tab0 = use_tab ? (unsigned long long*)(w + tab_off0) : nullptr;
    unsigned long long* tab1 = use_tab ? (unsigned long long*)(w + tab_off1) : nullptr;

    const int pairs = (N + 1) / 2;                       // 2 nodes per wave (k1)
    const int node_blocks = (pairs * 64 + 255) / 256;
    const int2* adj2 = (const int2*)adj;

    tanh_score_kernel<<<node_blocks, 256, 0, stream>>>(features, out, tab0,
                                                       escore0, none_rel,
                                                       adj, start, E, N);
    if (use_tab) {
        const int attn_blocks = (N * 64 + 255) / 256;    // 1 node per wave
        attn4_kernel<true><<<attn_blocks, 256, 0, stream>>>(
            tab0, out + D_FEAT, tab1, adj2, start, escore0, escore1, none_rel, N);
        attn4_kernel<false><<<attn_blocks, 256, 0, stream>>>(
            tab1, out + 2 * D_FEAT, nullptr, adj2, start, escore1, nullptr, none_rel, N);
    } else {
        attn_f32_kernel<<<node_blocks, 256, 0, stream>>>(
            out, out + D_FEAT, adj2, start, escore0, escore1, none_rel, N);
        attn_f32_kernel<<<node_blocks, 256, 0, stream>>>(
            out + D_FEAT, out + 2 * D_FEAT, adj2, start, escore1, nullptr, none_rel, N);
    }
}

// Round 4
// 158.621 us; speedup vs baseline: 1.0606x; 1.0606x over previous
//
#include <hip/hip_runtime.h>
#include <hip/hip_fp16.h>
#include <math.h>

#define D_FEAT 100
#define ROW_STRIDE 300     // 3 * D_FEAT concatenated output blocks
#define ROWB 208u          // f16 table row: 13 x 16B blocks; block k = feats
                           // 8k..8k+7 as f16 (block 12: feats 96..99 + 4 zero)

// ---------------------------------------------------------------------------
// fast tanh via hardware exp (inputs bounded, |2x| <= ~12)
// ---------------------------------------------------------------------------
__device__ __forceinline__ float fast_tanh(float x) {
    float ax = fabsf(x);
    float e  = __expf(2.f * ax);
    float t  = 1.f - 2.f / (e + 1.f);
    return copysignf(t, x);
}

// f16 packing (RNE)
__device__ __forceinline__ unsigned pack_f16x2(float a, float b) {
    __half2 h = __floats2half2_rn(a, b);
    union { __half2 h; unsigned u; } cvt; cvt.h = h;
    return cvt.u;
}

// butterfly sum within each 32-lane half
__device__ __forceinline__ float half_reduce(float v) {
    #pragma unroll
    for (int off = 16; off; off >>= 1) v += __shfl_xor(v, off, 64);
    return v;
}

// ---------------------------------------------------------------------------
// Kernel 1: 2 nodes per wave + fused CSR binary search. (unchanged)
// ---------------------------------------------------------------------------
__global__ __launch_bounds__(256) void tanh_score_kernel(
    const float* __restrict__ features,
    float* __restrict__ out,
    unsigned long long* __restrict__ tab0,   // 208-B f16 row table or null
    float* __restrict__ escore0,             // per-node exp-score (always)
    const float* __restrict__ none_rel,
    const int* __restrict__ adj,
    int* __restrict__ startArr,
    int E, int N)
{
    int gtid = blockIdx.x * blockDim.x + threadIdx.x;
    if (gtid <= N) {                          // fused CSR
        if (gtid == N) startArr[N] = E;
        else {
            int lo = 0, hi = E;
            while (lo < hi) {
                int mid = (lo + hi) >> 1;
                if (adj[2 * mid] < gtid) lo = mid + 1; else hi = mid;
            }
            startArr[gtid] = lo;
        }
    }

    int waveId = gtid >> 6;
    int lane = threadIdx.x & 63;
    int h32  = lane >> 5;
    int l    = lane & 31;
    int n    = waveId * 2 + h32;
    const bool valid_n = (n < N);
    const bool fact = valid_n && (l >= 1) && (l <= 25);

    float x0 = 0.f, x1 = 0.f, x2 = 0.f, x3 = 0.f;
    if (fact) {
        float4 f = ((const float4*)(features + (size_t)n * D_FEAT))[l - 1];
        x0 = fast_tanh(f.x); x1 = fast_tanh(f.y);
        x2 = fast_tanh(f.z); x3 = fast_tanh(f.w);
        ((float4*)(out + (size_t)n * ROW_STRIDE))[l - 1] = make_float4(x0, x1, x2, x3);
    }
    if (tab0 && valid_n) {
        char* row = (char*)tab0 + (size_t)n * ROWB;
        if (l >= 1 && l <= 25) {
            unsigned long long q = (unsigned long long)pack_f16x2(x0, x1) |
                                   ((unsigned long long)pack_f16x2(x2, x3) << 32);
            *(unsigned long long*)(row + 8 * (l - 1)) = q;   // feats 4(l-1)..
        } else if (l == 26) {
            *(unsigned long long*)(row + 200) = 0ULL;        // zero pads 100..103
        }
    }

    float nx = 0.f, ny = 0.f, nz = 0.f, nw = 0.f;
    if (l >= 1 && l <= 25) {
        float4 v = ((const float4*)none_rel)[l - 1];
        nx = v.x; ny = v.y; nz = v.z; nw = v.w;
    }
    float ss = half_reduce(nx * nx + ny * ny + nz * nz + nw * nw);
    float inv_nr = 1.f / fmaxf(sqrtf(ss), 1e-12f);

    float dot = half_reduce(x0 * nx + x1 * ny + x2 * nz + x3 * nw) * inv_nr;
    float sq  = half_reduce(x0 * x0 + x1 * x1 + x2 * x2 + x3 * x3);
    if (l == 0 && valid_n) {
        float es = __expf(-dot / fmaxf(sqrtf(sq), 1e-12f));
        escore0[n] = es;
    }
}

// ---------------------------------------------------------------------------
// Kernel 2: fused attention layer, 2 nodes per wave (one per 32-lane half),
// 2 edges per pass per node, EXPLICIT batch-of-4-pass scheduling:
//   8 register shfls -> 4 named back-to-back uint4 gathers (all in flight)
//   -> 32 v_fma_mix.  (Round-3's MLP pattern inside round-2's low-overhead
//   frame: epilogue/tanh/staging amortize over 2 nodes per wave.)
//  Weights staged per-edge (w=0 beyond deg) => no masking in hot loop.
// ---------------------------------------------------------------------------
template <bool WRITE_TAB>
__global__ __launch_bounds__(256) void attn16_kernel(
    const unsigned long long* __restrict__ tab,   // prev 208-B f16 table
    float* __restrict__ outp,
    unsigned long long* __restrict__ tab_out,     // next table (WRITE_TAB)
    const int2* __restrict__ adj2,
    const int* __restrict__ start,
    const float* __restrict__ esc_in,             // per-node weights (f32)
    float* __restrict__ esc_out,                  // next weights (WRITE_TAB)
    const float* __restrict__ none_rel,
    int N)
{
    const int waveId = (int)((blockIdx.x * blockDim.x + threadIdx.x) >> 6);
    const int lane = threadIdx.x & 63;
    const int h32  = lane >> 5;
    const int l    = lane & 31;
    const int base = h32 << 5;
    const int n    = waveId * 2 + h32;
    const bool valid_n = (n < N);

    const bool act  = (l < 26);
    const int  wh   = (act && l >= 13) ? 1 : 0;   // which edge of the pair
    const int  sub  = act ? (l - 13 * wh) : 0;    // 16-B block within row
    const bool actA = (l < 13);

    int e0 = 0, e1 = 0;
    if (valid_n) { e0 = start[n]; e1 = start[n + 1]; }
    const int deg = e1 - e0;
    int maxdeg = deg;
    { int o = __shfl_xor(maxdeg, 32, 64); maxdeg = maxdeg > o ? maxdeg : o; }

    // stage cols + weights for up to 64 edges (lane l of half holds edge l)
    int   c0 = 0, c1 = 0;
    float w0 = 0.f, w1 = 0.f;
    if (l < deg)      { c0 = adj2[e0 + l].y;      w0 = esc_in[c0]; }
    if (l + 32 < deg) { c1 = adj2[e0 + l + 32].y; w1 = esc_in[c1]; }

    // denominator: sum of staged weights (zeros beyond deg)
    float dsum = half_reduce(w0 + w1);

    const char* tb = (const char*)tab;
    const unsigned suboff = (unsigned)(sub * 16);

    float a0=0.f,a1=0.f,a2=0.f,a3=0.f,a4=0.f,a5=0.f,a6=0.f,a7=0.f;

#define FMA8(V, W)                                                            \
    {                                                                         \
        const __half2* hv = (const __half2*)&(V);                             \
        a0 = fmaf(__low2float(hv[0]),  (W), a0);                              \
        a1 = fmaf(__high2float(hv[0]), (W), a1);                              \
        a2 = fmaf(__low2float(hv[1]),  (W), a2);                              \
        a3 = fmaf(__high2float(hv[1]), (W), a3);                              \
        a4 = fmaf(__low2float(hv[2]),  (W), a4);                              \
        a5 = fmaf(__high2float(hv[2]), (W), a5);                              \
        a6 = fmaf(__low2float(hv[3]),  (W), a6);                              \
        a7 = fmaf(__high2float(hv[3]), (W), a7);                              \
    }

// Batch of 4 passes = edges R..R+7 of each half's node.
// SRCOFF: staged-register lane offset (0 for c0/w0 block, -32 for c1/w1).
#define BATCH8(CST, WST, R, SRCOFF)                                           \
    {                                                                         \
        const int sA = base + (R) + 0 + (SRCOFF) + wh;                        \
        const int sB = base + (R) + 2 + (SRCOFF) + wh;                        \
        const int sC = base + (R) + 4 + (SRCOFF) + wh;                        \
        const int sD = base + (R) + 6 + (SRCOFF) + wh;                        \
        int   cA = __shfl((CST), sA, 64), cB = __shfl((CST), sB, 64);         \
        int   cC = __shfl((CST), sC, 64), cD = __shfl((CST), sD, 64);         \
        float wA = __shfl((WST), sA, 64), wB = __shfl((WST), sB, 64);         \
        float wC = __shfl((WST), sC, 64), wD = __shfl((WST), sD, 64);         \
        const uint4 vA = *(const uint4*)(tb + (size_t)((unsigned)cA * ROWB + suboff)); \
        const uint4 vB = *(const uint4*)(tb + (size_t)((unsigned)cB * ROWB + suboff)); \
        const uint4 vC = *(const uint4*)(tb + (size_t)((unsigned)cC * ROWB + suboff)); \
        const uint4 vD = *(const uint4*)(tb + (size_t)((unsigned)cD * ROWB + suboff)); \
        FMA8(vA, wA) FMA8(vB, wB) FMA8(vC, wC) FMA8(vD, wD)                   \
    }

    const int cap1 = maxdeg < 32 ? maxdeg : 32;
    for (int r = 0; r < cap1; r += 8) BATCH8(c0, w0, r, 0)
    const int cap2 = maxdeg < 64 ? maxdeg : 64;
    for (int r = 32; r < cap2; r += 8) BATCH8(c1, w1, r, -32)

#undef BATCH8

    // deg > 64 tail (~never): one edge per pass, group A accumulates
    for (int e = e0 + 64; e < e1; ++e) {
        int   c = adj2[e].y;
        float w = esc_in[c];
        const uint4 v = *(const uint4*)(tb + (size_t)((unsigned)c * ROWB + suboff));
        if (actA) FMA8(v, w)
        dsum += w;     // uniform across lanes (added after the reduce)
    }
#undef FMA8

    // ---- combine even/odd edge groups (lane l <-> lane l+-13) ----
    const int partner = base + (actA ? l + 13 : (act ? l - 13 : l));
    a0 += __shfl(a0, partner, 64);
    a1 += __shfl(a1, partner, 64);
    a2 += __shfl(a2, partner, 64);
    a3 += __shfl(a3, partner, 64);
    a4 += __shfl(a4, partner, 64);
    a5 += __shfl(a5, partner, 64);
    a6 += __shfl(a6, partner, 64);
    a7 += __shfl(a7, partner, 64);

    const float inv_d = (deg > 0) ? 1.f / dsum : 0.f;
    float r0 = fast_tanh(a0 * inv_d);
    float r1 = fast_tanh(a1 * inv_d);
    float r2 = fast_tanh(a2 * inv_d);
    float r3 = fast_tanh(a3 * inv_d);
    float r4 = fast_tanh(a4 * inv_d);
    float r5 = fast_tanh(a5 * inv_d);
    float r6 = fast_tanh(a6 * inv_d);
    float r7 = fast_tanh(a7 * inv_d);
    if (!actA) { r0=r1=r2=r3=r4=r5=r6=r7=0.f; }   // epilogue reduce correctness

    // ---- writes: f32 out (+ f16 table) ----
    if (valid_n && actA) {
        float4* orow = (float4*)(outp + (size_t)n * ROW_STRIDE);
        orow[2*l] = make_float4(r0, r1, r2, r3);          // feats 8l..8l+3
        if (l < 12)
            orow[2*l + 1] = make_float4(r4, r5, r6, r7);  // feats 8l+4..8l+7
        if constexpr (WRITE_TAB) {
            uint4* trow = (uint4*)((char*)tab_out + (size_t)n * ROWB);
            trow[l] = make_uint4(pack_f16x2(r0, r1), pack_f16x2(r2, r3),
                                 pack_f16x2(r4, r5), pack_f16x2(r6, r7));
            // lane 12: r4..r7 == 0 -> pads stay zero
        }
    }

    // ---- epilogue: next layer's exp-score ----
    if constexpr (WRITE_TAB) {
        float n0=0.f,n1=0.f,n2=0.f,n3=0.f,n4=0.f,n5=0.f,n6=0.f,n7=0.f;
        if (actA) {
            float4 u = *(const float4*)(none_rel + 8 * l);
            n0=u.x; n1=u.y; n2=u.z; n3=u.w;
            if (l < 12) {
                float4 v2 = *(const float4*)(none_rel + 8 * l + 4);
                n4=v2.x; n5=v2.y; n6=v2.z; n7=v2.w;
            }
        }
        float ss = half_reduce(n0*n0+n1*n1+n2*n2+n3*n3+n4*n4+n5*n5+n6*n6+n7*n7);
        float inv_nr = 1.f / fmaxf(sqrtf(ss), 1e-12f);
        float dot = half_reduce(r0*n0+r1*n1+r2*n2+r3*n3+r4*n4+r5*n5+r6*n6+r7*n7) * inv_nr;
        float sq  = half_reduce(r0*r0+r1*r1+r2*r2+r3*r3+r4*r4+r5*r5+r6*r6+r7*r7);
        if (l == 0 && valid_n) {
            float es = __expf(-dot / fmaxf(sqrtf(sq), 1e-12f));
            esc_out[n] = es;
        }
    }
}

// ---------------------------------------------------------------------------
// Fallback attention kernel (f32 path, only used when workspace is too small
// for the f16 tables).
// ---------------------------------------------------------------------------
__global__ __launch_bounds__(256) void attn_f32_kernel(
    const float* __restrict__ prev,          // f32 stride-300
    float* __restrict__ outp,
    const int2* __restrict__ adj2,
    const int* __restrict__ start,
    const float* __restrict__ escore_in,
    float* __restrict__ escore_out,
    const float* __restrict__ none_rel,
    int N)
{
    int waveId = (int)((blockIdx.x * blockDim.x + threadIdx.x) >> 6);
    int lane = threadIdx.x & 63;
    int h32  = lane >> 5;
    int l    = lane & 31;
    int n    = waveId * 2 + h32;
    const bool valid_n = (n < N);
    const bool fact = valid_n && (l >= 1) && (l <= 25);
    const int base = h32 << 5;

    int e0 = 0, e1 = 0;
    if (valid_n) { e0 = start[n]; e1 = start[n + 1]; }
    const int deg = e1 - e0;

    int   c0 = 0, c1 = 0;
    float w0 = 0.f, w1 = 0.f;
    if (l < deg)      { c0 = adj2[e0 + l].y;      w0 = escore_in[c0]; }
    if (l + 32 < deg) { c1 = adj2[e0 + l + 32].y; w1 = escore_in[c1]; }

    int maxdeg = deg;
    { int o = __shfl_xor(maxdeg, 32, 64); maxdeg = maxdeg > o ? maxdeg : o; }

    float d_acc = 0.f, a0 = 0.f, a1 = 0.f, a2 = 0.f, a3 = 0.f;
    const int cap1 = maxdeg < 32 ? maxdeg : 32;
    for (int r = 0; r < cap1; r += 8) {
        #pragma unroll
        for (int j = 0; j < 8; ++j) {
            int   i = r + j;
            int   c = __shfl(c0, base + i, 64);
            float w = __shfl(w0, base + i, 64);
            float p0 = 0.f, p1 = 0.f, p2 = 0.f, p3 = 0.f;
            if (fact && (i < deg)) {
                float4 v = ((const float4*)(prev + (size_t)c * ROW_STRIDE))[l - 1];
                p0 = v.x; p1 = v.y; p2 = v.z; p3 = v.w;
            }
            if (i >= deg) w = 0.f;
            d_acc += w;
            a0 += w * p0; a1 += w * p1; a2 += w * p2; a3 += w * p3;
        }
    }
    const int cap2 = maxdeg < 64 ? maxdeg : 64;
    for (int r = 32; r < cap2; r += 8) {
        #pragma unroll
        for (int j = 0; j < 8; ++j) {
            int   i = r + j;
            int   c = __shfl(c1, base + i - 32, 64);
            float w = __shfl(w1, base + i - 32, 64);
            float p0 = 0.f, p1 = 0.f, p2 = 0.f, p3 = 0.f;
            if (fact && (i < deg)) {
                float4 v = ((const float4*)(prev + (size_t)c * ROW_STRIDE))[l - 1];
                p0 = v.x; p1 = v.y; p2 = v.z; p3 = v.w;
            }
            if (i >= deg) w = 0.f;
            d_acc += w;
            a0 += w * p0; a1 += w * p1; a2 += w * p2; a3 += w * p3;
        }
    }
    for (int e = e0 + 64; e < e1; ++e) {
        int c = adj2[e].y;
        float w = escore_in[c];
        float p0 = 0.f, p1 = 0.f, p2 = 0.f, p3 = 0.f;
        if (fact) {
            float4 v = ((const float4*)(prev + (size_t)c * ROW_STRIDE))[l - 1];
            p0 = v.x; p1 = v.y; p2 = v.z; p3 = v.w;
        }
        d_acc += w;
        a0 += w * p0; a1 += w * p1; a2 += w * p2; a3 += w * p3;
    }

    const float inv_d = (deg > 0) ? 1.f / d_acc : 0.f;
    float r0 = fast_tanh(a0 * inv_d);
    float r1 = fast_tanh(a1 * inv_d);
    float r2 = fast_tanh(a2 * inv_d);
    float r3 = fast_tanh(a3 * inv_d);
    if (fact) {
        ((float4*)(outp + (size_t)n * ROW_STRIDE))[l - 1] = make_float4(r0, r1, r2, r3);
    } else {
        r0 = r1 = r2 = r3 = 0.f;
    }

    if (escore_out) {
        float nx = 0.f, ny = 0.f, nz = 0.f, nw = 0.f;
        if (l >= 1 && l <= 25) {
            float4 v = ((const float4*)none_rel)[l - 1];
            nx = v.x; ny = v.y; nz = v.z; nw = v.w;
        }
        float ss = half_reduce(nx * nx + ny * ny + nz * nz + nw * nw);
        float inv_nr = 1.f / fmaxf(sqrtf(ss), 1e-12f);
        float dot = half_reduce(r0 * nx + r1 * ny + r2 * nz + r3 * nw) * inv_nr;
        float sq  = half_reduce(r0 * r0 + r1 * r1 + r2 * r2 + r3 * r3);
        if (l == 0 && valid_n) {
            float es = __expf(-dot / fmaxf(sqrtf(sq), 1e-12f));
            escore_out[n] = es;
        }
    }
}

// ---------------------------------------------------------------------------
extern "C" void kernel_launch(void* const* d_in, const int* in_sizes, int n_in,
                              void* d_out, int out_size, void* d_ws, size_t ws_size,
                              hipStream_t stream) {
    const float* features = (const float*)d_in[0];
    // d_in[1] = rel_emb: unused by the reference
    const int*   adj      = (const int*)d_in[2];
    const float* none_rel = (const float*)d_in[3];
    float* out = (float*)d_out;

    const int N = in_sizes[0] / D_FEAT;   // 50000
    const int E = in_sizes[2] / 2;        // 800000

    // ws: start[N+1] | escore0[N] | escore1[N] | tab0[N*208B] | tab1[N*208B]
    size_t off = 0;
    auto take = [&](size_t bytes) { size_t o = off; off = (off + bytes + 15) & ~(size_t)15; return o; };
    char* w = (char*)d_ws;
    int*   start   = (int*)  (w + take(sizeof(int)   * (size_t)(N + 1)));
    float* escore0 = (float*)(w + take(sizeof(float) * (size_t)N));
    float* escore1 = (float*)(w + take(sizeof(float) * (size_t)N));
    size_t tab_off0 = take((size_t)N * ROWB);
    size_t tab_off1 = take((size_t)N * ROWB);
    const bool use_tab = (ws_size >= off);
    unsigned long long* tab0 = use_tab ? (unsigned long long*)(w + tab_off0) : nullptr;
    unsigned long long* tab1 = use_tab ? (unsigned long long*)(w + tab_off1) : nullptr;

    const int pairs = (N + 1) / 2;                       // 2 nodes per wave
    const int node_blocks = (pairs * 64 + 255) / 256;
    const int2* adj2 = (const int2*)adj;

    tanh_score_kernel<<<node_blocks, 256, 0, stream>>>(features, out, tab0,
                                                       escore0, none_rel,
                                                       adj, start, E, N);
    if (use_tab) {
        attn16_kernel<true><<<node_blocks, 256, 0, stream>>>(
            tab0, out + D_FEAT, tab1, adj2, start, escore0, escore1, none_rel, N);
        attn16_kernel<false><<<node_blocks, 256, 0, stream>>>(
            tab1, out + 2 * D_FEAT, nullptr, adj2, start, escore1, nullptr, none_rel, N);
    } else {
        attn_f32_kernel<<<node_blocks, 256, 0, stream>>>(
            out, out + D_FEAT, adj2, start, escore0, escore1, none_rel, N);
        attn_f32_kernel<<<node_blocks, 256, 0, stream>>>(
            out + D_FEAT, out + 2 * D_FEAT, adj2, start, escore1, nullptr, none_rel, N);
    }
}